// Round 5
// baseline (203.119 us; speedup 1.0000x reference)
//
#include <hip/hip_runtime.h>

#define N_AG    128
#define H_DIM   128
#define IN_DIM  132
#define P_PAIRS 8128   // 128*127/2
#define BLOCKS  1016   // P_PAIRS / 8 pairs-per-block

typedef float f32x4 __attribute__((ext_vector_type(4)));

// closed-form recovery of (i,j) from pair index p (np.triu_indices order)
__device__ __forceinline__ void pair_from_p(int p, int& i, int& j) {
    int t = P_PAIRS - 1 - p;                  // reverse index: t=0 is (N-2,N-1)
    float kf = (sqrtf(8.f * (float)t + 1.f) - 1.f) * 0.5f;
    int k = (int)kf;
    while ((k + 1) * (k + 2) / 2 <= t) ++k;   // fixup fp error
    while (k * (k + 1) / 2 > t) --k;
    i = N_AG - 2 - k;
    j = N_AG - 1 - (t - k * (k + 1) / 2);
}

__global__ void zero_out_kernel(float* out) { out[threadIdx.x] = 0.f; }

// One pair per 32-lane half-wave; thread owns output columns 4*lane..4*lane+3.
// Each half-wave is fully self-contained (private xs copy, private h1 buffer)
// -> ZERO __syncthreads; each half-wave is one uninterrupted 135 KB read stream.
__global__ __launch_bounds__(256, 4) void fused_mlp_kernel(
    const float* __restrict__ state,
    const float* __restrict__ actions,
    const float* __restrict__ W1,
    const float* __restrict__ b1,
    const float* __restrict__ W2,
    const float* __restrict__ b2,
    const float* __restrict__ W3,
    const float* __restrict__ b3,
    float* __restrict__ out)
{
    const int t    = threadIdx.x;
    const int slot = t >> 5;            // pair slot within block, 0..7
    const int lane = t & 31;            // lane within half-wave
    const int p    = blockIdx.x * 8 + slot;

    __shared__ float xss[8][128];       // per-slot private state copy
    __shared__ float h1s[8][128];       // per-slot hidden 1

    #pragma unroll
    for (int q = 0; q < 4; ++q)
        xss[slot][lane + 32 * q] = state[lane + 32 * q];

    int i, j;
    pair_from_p(p, i, j);
    const float x128 = (float)i;
    const float x129 = (float)j;
    const float x130 = actions[i];
    const float x131 = actions[j];

    __builtin_amdgcn_wave_barrier();    // ordering fence only (no runtime cost)

    // ---- layer 1: h1 = relu(x @ W1[p] + b1[p]) ----
    const f32x4* W1p = (const f32x4*)(W1 + (size_t)p * (IN_DIM * H_DIM));
    f32x4 acc = (f32x4)(0.f);
    #pragma unroll 8
    for (int r = 0; r < 128; ++r) {
        const float xv = xss[slot][r];
        const f32x4 w = __builtin_nontemporal_load(&W1p[r * 32 + lane]);
        acc.x = fmaf(xv, w.x, acc.x);
        acc.y = fmaf(xv, w.y, acc.y);
        acc.z = fmaf(xv, w.z, acc.z);
        acc.w = fmaf(xv, w.w, acc.w);
    }
    {   // tail rows 128..131: [i, j, a_i, a_j]
        const f32x4 wA = __builtin_nontemporal_load(&W1p[128 * 32 + lane]);
        const f32x4 wB = __builtin_nontemporal_load(&W1p[129 * 32 + lane]);
        const f32x4 wC = __builtin_nontemporal_load(&W1p[130 * 32 + lane]);
        const f32x4 wD = __builtin_nontemporal_load(&W1p[131 * 32 + lane]);
        acc.x = fmaf(x128, wA.x, acc.x); acc.y = fmaf(x128, wA.y, acc.y);
        acc.z = fmaf(x128, wA.z, acc.z); acc.w = fmaf(x128, wA.w, acc.w);
        acc.x = fmaf(x129, wB.x, acc.x); acc.y = fmaf(x129, wB.y, acc.y);
        acc.z = fmaf(x129, wB.z, acc.z); acc.w = fmaf(x129, wB.w, acc.w);
        acc.x = fmaf(x130, wC.x, acc.x); acc.y = fmaf(x130, wC.y, acc.y);
        acc.z = fmaf(x130, wC.z, acc.z); acc.w = fmaf(x130, wC.w, acc.w);
        acc.x = fmaf(x131, wD.x, acc.x); acc.y = fmaf(x131, wD.y, acc.y);
        acc.z = fmaf(x131, wD.z, acc.z); acc.w = fmaf(x131, wD.w, acc.w);
    }
    const f32x4 b1v = *(const f32x4*)(b1 + (size_t)p * H_DIM + 4 * lane);
    f32x4 h1;
    h1.x = fmaxf(acc.x + b1v.x, 0.f);
    h1.y = fmaxf(acc.y + b1v.y, 0.f);
    h1.z = fmaxf(acc.z + b1v.z, 0.f);
    h1.w = fmaxf(acc.w + b1v.w, 0.f);
    *(f32x4*)&h1s[slot][4 * lane] = h1;

    __builtin_amdgcn_wave_barrier();    // ordering fence only

    // ---- layer 2: h2 = relu(h1 @ W2[p] + b2[p]) ----
    const f32x4* W2p = (const f32x4*)(W2 + (size_t)p * (H_DIM * H_DIM));
    acc = (f32x4)(0.f);
    #pragma unroll 8
    for (int k = 0; k < 128; ++k) {
        const float hv = h1s[slot][k];
        const f32x4 w = __builtin_nontemporal_load(&W2p[k * 32 + lane]);
        acc.x = fmaf(hv, w.x, acc.x);
        acc.y = fmaf(hv, w.y, acc.y);
        acc.z = fmaf(hv, w.z, acc.z);
        acc.w = fmaf(hv, w.w, acc.w);
    }
    const f32x4 b2v = *(const f32x4*)(b2 + (size_t)p * H_DIM + 4 * lane);
    f32x4 h2;
    h2.x = fmaxf(acc.x + b2v.x, 0.f);
    h2.y = fmaxf(acc.y + b2v.y, 0.f);
    h2.z = fmaxf(acc.z + b2v.z, 0.f);
    h2.w = fmaxf(acc.w + b2v.w, 0.f);

    // ---- layer 3: logits over the thread's own 4 rows, then 32-lane reduce ----
    const f32x4* W3p = (const f32x4*)(W3 + (size_t)p * (H_DIM * 2));
    const f32x4 wa = __builtin_nontemporal_load(&W3p[2 * lane]);      // rows 4l,4l+1
    const f32x4 wb = __builtin_nontemporal_load(&W3p[2 * lane + 1]);  // rows 4l+2,4l+3
    float l0 = h2.x * wa.x + h2.y * wa.z + h2.z * wb.x + h2.w * wb.z;
    float l1 = h2.x * wa.y + h2.y * wa.w + h2.z * wb.y + h2.w * wb.w;
    #pragma unroll
    for (int off = 16; off > 0; off >>= 1) {
        l0 += __shfl_xor(l0, off, 32);
        l1 += __shfl_xor(l1, off, 32);
    }
    if (lane == 0) {
        l0 += b3[2 * p];
        l1 += b3[2 * p + 1];
        const float m  = fmaxf(l0, l1);
        const float e0 = expf(l0 - m), e1 = expf(l1 - m);
        const float inv = 1.f / (e0 + e1);
        const float g0 = e0 * inv, g1 = e1 * inv;
        atomicAdd(&out[2 * i],     g0);
        atomicAdd(&out[2 * i + 1], g1);
        atomicAdd(&out[2 * j],     g0);
        atomicAdd(&out[2 * j + 1], g1);
    }
}

extern "C" void kernel_launch(void* const* d_in, const int* in_sizes, int n_in,
                              void* d_out, int out_size, void* d_ws, size_t ws_size,
                              hipStream_t stream) {
    const float* state   = (const float*)d_in[0];
    const float* actions = (const float*)d_in[1];
    const float* W1      = (const float*)d_in[2];
    const float* b1      = (const float*)d_in[3];
    const float* W2      = (const float*)d_in[4];
    const float* b2      = (const float*)d_in[5];
    const float* W3      = (const float*)d_in[6];
    const float* b3      = (const float*)d_in[7];
    float* out = (float*)d_out;

    zero_out_kernel<<<1, 256, 0, stream>>>(out);
    fused_mlp_kernel<<<BLOCKS, 256, 0, stream>>>(
        state, actions, W1, b1, W2, b2, W3, b3, out);
}